// Round 4
// baseline (131.325 us; speedup 1.0000x reference)
//
#include <hip/hip_runtime.h>
#include <math.h>

// FP contraction off: every op is an exactly-rounded IEEE op in fixed order ->
// bit-identical geometry in pass1 / pass2-main / pass2-rescan, and identical
// to the numpy float32 reference.
#pragma clang fp contract(off)

#define NUM_CLASSES 80
#define TB 64   // targets per image
#define NB 8    // batch

// IoU geometry (inter, union) — must be the same code everywhere.
__device__ __forceinline__ void geom(const float4& bb, float at,
                                     const float4& av, float aar,
                                     float& inter, float& u) {
  float w = fminf(bb.z, av.z) - fmaxf(bb.x, av.x);
  float h = fminf(bb.w, av.w) - fmaxf(bb.y, av.y);
  w = fmaxf(w, 0.0f);
  h = fmaxf(h, 0.0f);
  inter = w * h;
  u = (at + aar) - inter;
}

// pass 0: cxcywh -> xyxy; zero gmax bits (IoU >= 0 -> 0 is max-identity).
__global__ void pass0(const float* __restrict__ tgt,
                      float4* __restrict__ boxes,
                      int* __restrict__ gmaxbits) {
  int i = blockIdx.x * blockDim.x + threadIdx.x;
  if (i < NB * TB) {
    float cx = tgt[i*4+0], cy = tgt[i*4+1], w = tgt[i*4+2], h = tgt[i*4+3];
    boxes[i] = make_float4(cx - 0.5f*w, cy - 0.5f*h, cx + 0.5f*w, cy + 0.5f*h);
    gmaxbits[i] = 0;
  }
}

// pass 1: gmax[b][t] = round(max_a i/u) = max_a round(i/u)  (rounding is
// monotone). lane = gt box t; anchors stream wave-uniformly (scalar loads);
// running max kept as exact (i,u) pair via f64 cross-mult; ONE f32 div at end.
#define P1_WCHUNK 128   // anchors per wave
__global__ __launch_bounds__(256) void pass1(const float4* __restrict__ anchors,
                                             const float4* __restrict__ boxes,
                                             int* __restrict__ gmaxbits, int A) {
  int b = blockIdx.y;
  int lane = threadIdx.x & 63;
  int wv = __builtin_amdgcn_readfirstlane(threadIdx.x >> 6);
  int a0 = (blockIdx.x * 4 + wv) * P1_WCHUNK;

  float4 bb = boxes[b * TB + lane];
  float at = (bb.z - bb.x) * (bb.w - bb.y);

  // two independent accumulator pairs to break the serial compare chain
  double idA = 0.0, udA = 1.0, idB = 0.0, udB = 1.0;
#pragma unroll 4
  for (int j = 0; j < P1_WCHUNK; j += 2) {
    int a1 = a0 + j;     if (a1 > A - 1) a1 = A - 1;  // dup clamp: benign for max
    int a2 = a0 + j + 1; if (a2 > A - 1) a2 = A - 1;
    float4 av1 = anchors[a1];   // wave-uniform address -> scalar load
    float4 av2 = anchors[a2];
    float aar1 = (av1.z - av1.x) * (av1.w - av1.y);
    float aar2 = (av2.z - av2.x) * (av2.w - av2.y);
    float i1, u1, i2, u2;
    geom(bb, at, av1, aar1, i1, u1);
    geom(bb, at, av2, aar2, i2, u2);
    double i1d = (double)i1, u1d = (double)u1;
    double i2d = (double)i2, u2d = (double)u2;
    // exact: 24b x 24b products fit in f64
    if (i1d * udA > idA * u1d) { idA = i1d; udA = u1d; }
    if (i2d * udB > idB * u2d) { idB = i2d; udB = u2d; }
  }
  if (idB * udA > idA * udB) { idA = idB; udA = udB; }
  float m = (float)idA / (float)udA;   // one correctly-rounded div per lane
  atomicMax(gmaxbits + b * TB + lane, __float_as_int(m));
}

// pass 2: per (b, anchor): exact argmax over t (f64 cross-mult, strict > keeps
// first occurrence), `highest` via g's lower rounding boundary, rounded-tie
// repair via rare rescan, then labels + deltas.
#define P2_K 2
__global__ __launch_bounds__(256) void pass2(const float4* __restrict__ anchors,
                                             const float4* __restrict__ boxes,
                                             const int* __restrict__ gmaxbits,
                                             const int* __restrict__ labels,
                                             float* __restrict__ out, int A) {
  int b = blockIdx.y;
  __shared__ float4 sb[TB];
  __shared__ float  sa[TB];
  __shared__ double sglo[TB];   // lower rounding boundary of gmax (exact f64)
  __shared__ int    scl[TB];    // boundary inclusive? (ties-to-even parity)
  __shared__ int    sl[TB];
  int tid = threadIdx.x;
  if (tid < TB) {
    float4 bv = boxes[b*TB+tid];
    sb[tid] = bv;
    sa[tid] = (bv.z - bv.x) * (bv.w - bv.y);
    int gb = gmaxbits[b*TB+tid];
    if (gb == 0) {
      // g == 0 -> every iou rounds to 0 == g -> all anchors "highest"
      sglo[tid] = -1.0; scl[tid] = 1;
    } else {
      float g  = __int_as_float(gb);
      float gp = __int_as_float(gb - 1);
      sglo[tid] = 0.5 * ((double)g + (double)gp);  // exact: <=25-bit sum
      scl[tid]  = ((gb & 1) == 0) ? 1 : 0;
    }
    sl[tid] = labels[b*TB+tid];
  }
  __syncthreads();

  int abase = blockIdx.x * (P2_K * 256) + tid;
  float4 av[P2_K]; float aar[P2_K];
  double id[P2_K], ud[P2_K];
  int    ts[P2_K];
  bool   flag[P2_K], high[P2_K];
#pragma unroll
  for (int k = 0; k < P2_K; ++k) {
    int a = abase + k*256; if (a > A-1) a = A-1;  // dup compute; store guarded
    av[k]  = anchors[a];
    aar[k] = (av[k].z - av[k].x) * (av[k].w - av[k].y);
    id[k] = 0.0; ud[k] = 1.0; ts[k] = 0; flag[k] = false; high[k] = false;
  }

#pragma unroll 4
  for (int t = 0; t < TB; ++t) {
    float4 bbv = sb[t];
    float  at  = sa[t];
    double glo = sglo[t];
    bool   cl  = scl[t] != 0;
#pragma unroll
    for (int k = 0; k < P2_K; ++k) {
      float inter, u;
      geom(bbv, at, av[k], aar[k], inter, u);
      double i_d = (double)inter, u_d = (double)u;
      double p1 = i_d * ud[k];   // exact
      double p2 = id[k] * u_d;   // exact
      // rounded-tie band: any t whose value rounds to the final max lies
      // within 2^-23 rel of the then-best -> 2^-22 band provably catches it.
      // Exact equality (dd==0) needs no repair (strict > keeps first).
      double dd = fabs(p2 - p1);
      double pm = fmax(p1, p2);
      flag[k] = flag[k] | ((dd != 0.0) & (dd <= pm * 2.384185791015625e-07));
      if (p1 > p2) { id[k] = i_d; ud[k] = u_d; ts[k] = t; }
      // round(v)==g  <=>  v >= glo (upper side automatic: round(v) <= g)
      double ph = glo * u_d;     // exact: <=26-bit x 24-bit
      high[k] = high[k] | (i_d > ph) | (cl & (i_d == ph));
    }
  }

#pragma unroll
  for (int k = 0; k < P2_K; ++k) {
    int a = abase + k*256;
    if (a >= A) break;

    float i32 = (float)id[k], u32 = (float)ud[k];  // exact back-conversions
    float M = i32 / u32;       // one correctly-rounded div per anchor
    int mid = ts[k];

    if (flag[k]) {
      // exact repair: first t with round(v_t) == M (np argmax semantics)
      int Mb = __float_as_int(M);
      double Mlo; bool clM;
      if (Mb == 0) { Mlo = -1.0; clM = true; }
      else {
        float Mp = __int_as_float(Mb - 1);
        Mlo = 0.5 * ((double)M + (double)Mp);
        clM = ((Mb & 1) == 0);
      }
      for (int t = 0; t < TB; ++t) {
        float inter, u;
        geom(sb[t], sa[t], av[k], aar[k], inter, u);
        double i_d = (double)inter, u_d = (double)u;
        double p = Mlo * u_d;
        bool hit = (i_d > p) | (clM & (i_d == p));
        if (hit) { mid = t; break; }
      }
    }

    int lab;
    if (high[k])        lab = 1;   // low-quality matches become positives
    else if (M >= 0.5f) lab = 1;
    else if (M >= 0.4f) lab = -1;
    else                lab = 0;

    int out_label = (lab == 1) ? sl[mid] : ((lab == 0) ? NUM_CLASSES : -1);
    out[(size_t)b * A + a] = (float)out_label;

    float4 mb = sb[mid];
    float sw = av[k].z - av[k].x, sh2 = av[k].w - av[k].y;
    float sx = av[k].x + 0.5f*sw, sy = av[k].y + 0.5f*sh2;
    float tw = mb.z - mb.x,       th = mb.w - mb.y;
    float tx = mb.x + 0.5f*tw,    ty = mb.y + 0.5f*th;
    float4 d;
    d.x = (tx - sx) / sw;
    d.y = (ty - sy) / sh2;
    d.z = logf(tw / sw);
    d.w = logf(th / sh2);
    *(float4*)(out + (size_t)NB * A + ((size_t)b * A + a) * 4) = d;
  }
}

extern "C" void kernel_launch(void* const* d_in, const int* in_sizes, int n_in,
                              void* d_out, int out_size, void* d_ws, size_t ws_size,
                              hipStream_t stream) {
  const float* anchors    = (const float*)d_in[0];
  const float* tgt_boxes  = (const float*)d_in[1];
  const int*   tgt_labels = (const int*)d_in[2];
  int A = in_sizes[0] / 4;

  float*  ws       = (float*)d_ws;
  float4* boxes    = (float4*)ws;                  // NB*TB float4
  int*    gmaxbits = (int*)(ws + NB * TB * 4);     // NB*TB int
  float*  out      = (float*)d_out;

  pass0<<<2, 256, 0, stream>>>(tgt_boxes, boxes, gmaxbits);
  dim3 g1((A + 4 * P1_WCHUNK - 1) / (4 * P1_WCHUNK), NB);
  pass1<<<g1, 256, 0, stream>>>((const float4*)anchors, boxes, gmaxbits, A);
  dim3 g2((A + P2_K * 256 - 1) / (P2_K * 256), NB);
  pass2<<<g2, 256, 0, stream>>>((const float4*)anchors, boxes, gmaxbits,
                                tgt_labels, out, A);
}